// Round 1
// baseline (465.782 us; speedup 1.0000x reference)
//
#include <hip/hip_runtime.h>
#include <math.h>

#define N_QUBITS 24
#define N_BLOCKS 4
#define NSTATE (1 << N_QUBITS)

// Qubit q <-> flat-index bit (23 - q)  (row-major reshape of (2,)*24).
// Per block, gates reordered (valid by commutation) into the staircase:
//   RY(0); for q=1..23: RY(q); CNOT(q-1, q)
// split into 3 passes:
//   P1: qubits 0..8   -> bits 15..23
//   P2: qubits 9..16  -> bits 7..14   (CNOT(8,9) control = bit 15, diagonal)
//   P3: qubits 17..23 -> bits 0..6    (CNOT(16,17) control = bit 7, diagonal)

// ---------------- Pass 1: qubits 0..8 (bits 15..23) ----------------
// Tile: 512 rows (bits 15..23) x 16 cols (bits 0..3); blockIdx covers bits 4..14.
template <bool INIT>
__global__ __launch_bounds__(256)
void pass1_kernel(float* __restrict__ state, const float* __restrict__ angles, int blk_b) {
    __shared__ float tile[512][17];
    const int tid = threadIdx.x;
    const int base_low = blockIdx.x << 4;

    if (INIT) {
        if (blockIdx.x != 0) {
            // input is delta at index 0 -> this tile's output is all zeros
            for (int r0 = 0; r0 < 512; r0 += 16) {
                int row = r0 + (tid >> 4), col = tid & 15;
                state[base_low + col + (row << 15)] = 0.0f;
            }
            return;
        }
        for (int i = tid; i < 512 * 17; i += 256) (&tile[0][0])[i] = 0.0f;
        __syncthreads();
        if (tid == 0) tile[0][0] = 1.0f;
        __syncthreads();
    } else {
        for (int r0 = 0; r0 < 512; r0 += 16) {
            int row = r0 + (tid >> 4), col = tid & 15;
            tile[row][col] = state[base_low + col + (row << 15)];
        }
        __syncthreads();
    }

    const float* ang = angles + blk_b * N_QUBITS;

    // RY(0) on row bit 8
    {
        float s, c;
        sincosf(0.5f * ang[0], &s, &c);
        for (int i = tid; i < 4096; i += 256) {
            int col = i & 15, pr = i >> 4;               // pr in [0,256)
            float v0 = tile[pr][col], v1 = tile[pr + 256][col];
            tile[pr][col]       = c * v0 - s * v1;
            tile[pr + 256][col] = s * v0 + c * v1;
        }
        __syncthreads();
    }
    // q = 1..8: fused RY(q) then CNOT(q-1,q): quad on row bits (bt+1=ctrl, bt=tgt)
    for (int q = 1; q <= 8; ++q) {
        float s, c;
        sincosf(0.5f * ang[q], &s, &c);
        int bt = 8 - q;                                  // 7..0
        for (int i = tid; i < 2048; i += 256) {
            int col = i & 15, qr = i >> 4;               // qr in [0,128)
            int low = qr & ((1 << bt) - 1);
            int r00 = ((qr >> bt) << (bt + 2)) | low;
            int r01 = r00 | (1 << bt);
            int r10 = r00 | (2 << bt);
            int r11 = r00 | (3 << bt);
            float v00 = tile[r00][col], v01 = tile[r01][col];
            float v10 = tile[r10][col], v11 = tile[r11][col];
            tile[r00][col] = c * v00 - s * v01;
            tile[r01][col] = s * v00 + c * v01;
            // ctrl=1 half: RY then swap (CNOT)
            tile[r10][col] = s * v10 + c * v11;
            tile[r11][col] = c * v10 - s * v11;
        }
        __syncthreads();
    }

    for (int r0 = 0; r0 < 512; r0 += 16) {
        int row = r0 + (tid >> 4), col = tid & 15;
        state[base_low + col + (row << 15)] = tile[row][col];
    }
}

// ---------------- Pass 2: qubits 9..16 (bits 7..14) ----------------
// Tile: 256 rows (bits 7..14) x 32 cols (bits 0..4); blockIdx covers bits 5..6 and 15..23.
__global__ __launch_bounds__(256)
void pass2_kernel(float* __restrict__ state, const float* __restrict__ angles, int blk_b) {
    __shared__ float tile[256][33];
    const int tid = threadIdx.x;
    const int hi = blockIdx.x >> 2;                      // bits 15..23
    const int c2 = blockIdx.x & 3;                       // bits 5..6
    const int base = (hi << 15) | (c2 << 5);
    const int ctrl15 = hi & 1;                           // global bit 15

    for (int r0 = 0; r0 < 256; r0 += 8) {
        int row = r0 + (tid >> 5), col = tid & 31;
        tile[row][col] = state[base + col + (row << 7)];
    }
    __syncthreads();

    const float* ang = angles + blk_b * N_QUBITS;

    // RY(9) fused with CNOT(8,9) (diagonal control = bit 15): row bit 7
    {
        float s, c;
        sincosf(0.5f * ang[9], &s, &c);
        for (int i = tid; i < 4096; i += 256) {
            int col = i & 31, pr = i >> 5;               // pr in [0,128)
            float v0 = tile[pr][col], v1 = tile[pr + 128][col];
            float o0 = c * v0 - s * v1;
            float o1 = s * v0 + c * v1;
            if (ctrl15) { tile[pr][col] = o1; tile[pr + 128][col] = o0; }
            else        { tile[pr][col] = o0; tile[pr + 128][col] = o1; }
        }
        __syncthreads();
    }
    // q = 10..16: fused quads on row bits (bt+1, bt), bt = 16-q
    for (int q = 10; q <= 16; ++q) {
        float s, c;
        sincosf(0.5f * ang[q], &s, &c);
        int bt = 16 - q;                                 // 6..0
        for (int i = tid; i < 2048; i += 256) {
            int col = i & 31, qr = i >> 5;               // qr in [0,64)
            int low = qr & ((1 << bt) - 1);
            int r00 = ((qr >> bt) << (bt + 2)) | low;
            int r01 = r00 | (1 << bt);
            int r10 = r00 | (2 << bt);
            int r11 = r00 | (3 << bt);
            float v00 = tile[r00][col], v01 = tile[r01][col];
            float v10 = tile[r10][col], v11 = tile[r11][col];
            tile[r00][col] = c * v00 - s * v01;
            tile[r01][col] = s * v00 + c * v01;
            tile[r10][col] = s * v10 + c * v11;
            tile[r11][col] = c * v10 - s * v11;
        }
        __syncthreads();
    }

    for (int r0 = 0; r0 < 256; r0 += 8) {
        int row = r0 + (tid >> 5), col = tid & 31;
        state[base + col + (row << 7)] = tile[row][col];
    }
}

// ---------------- Pass 3: qubits 17..23 (bits 0..6) ----------------
// One wave owns a contiguous 128-float group: lane holds e = lane (a0) and e = lane+64 (a1).
// e-bit 6 = register axis; e-bits 0..5 = lane bits. Control bit 7 = group parity.
template <bool SQUARE>
__global__ __launch_bounds__(256)
void pass3_kernel(float* __restrict__ state, const float* __restrict__ angles, int blk_b) {
    const int lane = threadIdx.x & 63;
    const int wid = threadIdx.x >> 6;
    const int nwaves = (gridDim.x * blockDim.x) >> 6;
    const int gwave = blockIdx.x * (blockDim.x >> 6) + wid;
    const float* ang = angles + blk_b * N_QUBITS;

    float s[7], c[7];
#pragma unroll
    for (int j = 0; j < 7; ++j) sincosf(0.5f * ang[17 + j], &s[j], &c[j]);

    for (int g = gwave; g < (NSTATE >> 7); g += nwaves) {
        const int base = g << 7;
        float a0 = state[base + lane];
        float a1 = state[base + 64 + lane];

        // RY(17) on e-bit 6 (register axis), then CNOT(16,17) with ctrl = global bit 7 = g&1
        {
            float t0 = c[0] * a0 - s[0] * a1;
            float t1 = s[0] * a0 + c[0] * a1;
            if (g & 1) { a0 = t1; a1 = t0; }
            else       { a0 = t0; a1 = t1; }
        }
#pragma unroll
        for (int q = 18; q <= 23; ++q) {
            const int j = q - 17;
            const int bt = 23 - q;                       // 5..0
            // RY(q) on e-bit bt (lane bit)
            {
                float p0 = __shfl_xor(a0, 1 << bt);
                float p1 = __shfl_xor(a1, 1 << bt);
                float sgn = ((lane >> bt) & 1) ? s[j] : -s[j];
                a0 = fmaf(sgn, p0, c[j] * a0);
                a1 = fmaf(sgn, p1, c[j] * a1);
            }
            // CNOT(q-1, q): ctrl bit = bt+1
            if (q == 18) {
                // ctrl = e-bit 6 = register axis: only a1 flips across bit bt
                a1 = __shfl_xor(a1, 1 << bt);
            } else {
                const int bc = bt + 1;
                float p0 = __shfl_xor(a0, 1 << bt);
                float p1 = __shfl_xor(a1, 1 << bt);
                bool cb = (lane >> bc) & 1;
                a0 = cb ? p0 : a0;
                a1 = cb ? p1 : a1;
            }
        }
        if (SQUARE) { a0 *= a0; a1 *= a1; }
        state[base + lane] = a0;
        state[base + 64 + lane] = a1;
    }
}

extern "C" void kernel_launch(void* const* d_in, const int* in_sizes, int n_in,
                              void* d_out, int out_size, void* d_ws, size_t ws_size,
                              hipStream_t stream) {
    const float* angles = (const float*)d_in[0];
    float* state = (float*)d_out;   // state lives in d_out; final pass squares in place

    for (int b = 0; b < N_BLOCKS; ++b) {
        if (b == 0)
            pass1_kernel<true><<<2048, 256, 0, stream>>>(state, angles, b);
        else
            pass1_kernel<false><<<2048, 256, 0, stream>>>(state, angles, b);

        pass2_kernel<<<2048, 256, 0, stream>>>(state, angles, b);

        if (b == N_BLOCKS - 1)
            pass3_kernel<true><<<2048, 256, 0, stream>>>(state, angles, b);
        else
            pass3_kernel<false><<<2048, 256, 0, stream>>>(state, angles, b);
    }
}

// Round 2
// 339.793 us; speedup vs baseline: 1.3708x; 1.3708x over previous
//
#include <hip/hip_runtime.h>
#include <math.h>

#define N_QUBITS 24
#define N_BLOCKS 4
#define NSTATE (1 << N_QUBITS)

// Qubit q <-> flat-index bit (23 - q)  (row-major reshape of (2,)*24).
// Per block, gates reordered (valid by commutation) into the staircase:
//   RY(0); for q=1..23: RY(q); CNOT(q-1, q)
// split into 2 passes:
//   P1 : qubits 0..8   -> bits 15..23  (LDS tile, unchanged from R1)
//   P23: qubits 9..23  -> bits 0..14   (register-resident, 3 LDS transposes;
//                                       CNOT(8,9) control = bit 15, diagonal)

// ---------------- Pass 1: qubits 0..8 (bits 15..23) ----------------
template <bool INIT>
__global__ __launch_bounds__(256)
void pass1_kernel(float* __restrict__ state, const float* __restrict__ angles, int blk_b) {
    __shared__ float tile[512][17];
    const int tid = threadIdx.x;
    const int base_low = blockIdx.x << 4;

    if (INIT) {
        if (blockIdx.x != 0) {
            for (int r0 = 0; r0 < 512; r0 += 16) {
                int row = r0 + (tid >> 4), col = tid & 15;
                state[base_low + col + (row << 15)] = 0.0f;
            }
            return;
        }
        for (int i = tid; i < 512 * 17; i += 256) (&tile[0][0])[i] = 0.0f;
        __syncthreads();
        if (tid == 0) tile[0][0] = 1.0f;
        __syncthreads();
    } else {
        for (int r0 = 0; r0 < 512; r0 += 16) {
            int row = r0 + (tid >> 4), col = tid & 15;
            tile[row][col] = state[base_low + col + (row << 15)];
        }
        __syncthreads();
    }

    const float* ang = angles + blk_b * N_QUBITS;

    {
        float s, c;
        sincosf(0.5f * ang[0], &s, &c);
        for (int i = tid; i < 4096; i += 256) {
            int col = i & 15, pr = i >> 4;
            float v0 = tile[pr][col], v1 = tile[pr + 256][col];
            tile[pr][col]       = c * v0 - s * v1;
            tile[pr + 256][col] = s * v0 + c * v1;
        }
        __syncthreads();
    }
    for (int q = 1; q <= 8; ++q) {
        float s, c;
        sincosf(0.5f * ang[q], &s, &c);
        int bt = 8 - q;
        for (int i = tid; i < 2048; i += 256) {
            int col = i & 15, qr = i >> 4;
            int low = qr & ((1 << bt) - 1);
            int r00 = ((qr >> bt) << (bt + 2)) | low;
            int r01 = r00 | (1 << bt);
            int r10 = r00 | (2 << bt);
            int r11 = r00 | (3 << bt);
            float v00 = tile[r00][col], v01 = tile[r01][col];
            float v10 = tile[r10][col], v11 = tile[r11][col];
            tile[r00][col] = c * v00 - s * v01;
            tile[r01][col] = s * v00 + c * v01;
            tile[r10][col] = s * v10 + c * v11;
            tile[r11][col] = c * v10 - s * v11;
        }
        __syncthreads();
    }

    for (int r0 = 0; r0 < 512; r0 += 16) {
        int row = r0 + (tid >> 4), col = tid & 15;
        state[base_low + col + (row << 15)] = tile[row][col];
    }
}

// ---------------- Pass 2+3 fused: qubits 9..23 (bits 0..14) ----------------
// Workgroup = 512 threads, chunk = 32768 contiguous floats, 64 regs/thread.
// Swizzle: XOR bits 6..10 and 11..14 into bank bits 0..4 -> every transpose
// pattern is <=2-way (free).
#define SWZ(e) ((e) ^ (((e) >> 6) & 31) ^ (((e) >> 11) & 31))

// RY on reg bit 5 (pairs r, r|32), then conditional swap (CNOT with external ctrl).
__device__ __forceinline__ void pair_top(float (&a)[64], float s, float c, int swap) {
#pragma unroll
    for (int r = 0; r < 32; ++r) {
        float v0 = a[r], v1 = a[r | 32];
        float o0 = c * v0 - s * v1;
        float o1 = s * v0 + c * v1;
        a[r]      = swap ? o1 : o0;
        a[r | 32] = swap ? o0 : o1;
    }
}

// Fused RY(tgt = reg bit BT) then CNOT(ctrl = reg bit BT+1, tgt = reg bit BT).
template <int BT>
__device__ __forceinline__ void quad_gate(float (&a)[64], float s, float c) {
#pragma unroll
    for (int g = 0; g < 16; ++g) {
        int lo  = g & ((1 << BT) - 1);
        int r00 = ((g >> BT) << (BT + 2)) | lo;
        int r01 = r00 | (1 << BT);
        int r10 = r00 | (2 << BT);
        int r11 = r00 | (3 << BT);
        float v00 = a[r00], v01 = a[r01], v10 = a[r10], v11 = a[r11];
        a[r00] = c * v00 - s * v01;
        a[r01] = s * v00 + c * v01;
        a[r10] = s * v10 + c * v11;   // ctrl=1 half: RY then swap (CNOT)
        a[r11] = c * v10 - s * v11;
    }
}

template <bool SQUARE>
__global__ __launch_bounds__(512)
void pass23_kernel(float* __restrict__ state, const float* __restrict__ angles, int blk_b) {
    __shared__ float lds[32768];
    const int tid  = threadIdx.x;
    const int lane = tid & 63;
    const int w    = tid >> 6;                   // 0..7
    const size_t chunk = blockIdx.x;             // 0..511, covers bits 15..23
    float* __restrict__ base = state + (chunk << 15);
    const int c15 = (int)chunk & 1;              // logical bit 15 (= qubit 8)
    const float* ang = angles + blk_b * N_QUBITS;

    float a[64];

    // load: regs = e9..14, w = e6..8, lane = e0..5 (256B contiguous per wave-instr)
#pragma unroll
    for (int r = 0; r < 64; ++r)
        a[r] = base[(r << 9) | (w << 6) | lane];

    float s, c;
    // ---- phase 1: qubits 9..14 on reg bits (e9..14)
    sincosf(0.5f * ang[9], &s, &c);  pair_top(a, s, c, c15);        // RY(9)+CNOT(8,9)
    sincosf(0.5f * ang[10], &s, &c); quad_gate<4>(a, s, c);
    sincosf(0.5f * ang[11], &s, &c); quad_gate<3>(a, s, c);
    sincosf(0.5f * ang[12], &s, &c); quad_gate<2>(a, s, c);
    sincosf(0.5f * ang[13], &s, &c); quad_gate<1>(a, s, c);
    sincosf(0.5f * ang[14], &s, &c); quad_gate<0>(a, s, c);

    // ---- T1: -> regs = e3..8, lanes = e9..14, w = e0..2
#pragma unroll
    for (int r = 0; r < 64; ++r) {
        int e = (r << 9) | (w << 6) | lane;
        lds[SWZ(e)] = a[r];
    }
    __syncthreads();
#pragma unroll
    for (int r = 0; r < 64; ++r) {
        int e = (lane << 9) | (r << 3) | w;
        a[r] = lds[SWZ(e)];
    }

    // ---- phase 2: qubits 15..20 on reg bits (e3..8)
    sincosf(0.5f * ang[15], &s, &c); pair_top(a, s, c, lane & 1);   // RY(15)+CNOT(14,15), ctrl e9
    sincosf(0.5f * ang[16], &s, &c); quad_gate<4>(a, s, c);
    sincosf(0.5f * ang[17], &s, &c); quad_gate<3>(a, s, c);
    sincosf(0.5f * ang[18], &s, &c); quad_gate<2>(a, s, c);
    sincosf(0.5f * ang[19], &s, &c); quad_gate<1>(a, s, c);
    sincosf(0.5f * ang[20], &s, &c); quad_gate<0>(a, s, c);

    // ---- T2: -> regs = e0..5, lanes = e6..11, w = e12..14
    __syncthreads();
#pragma unroll
    for (int r = 0; r < 64; ++r) {
        int e = (lane << 9) | (r << 3) | w;
        lds[SWZ(e)] = a[r];
    }
    __syncthreads();
#pragma unroll
    for (int r = 0; r < 64; ++r) {
        int e = (w << 12) | (lane << 6) | r;
        a[r] = lds[SWZ(e)];
    }

    // ---- phase 3: qubits 21..23 on reg bits (e0..2, ctrl e3 in regs)
    sincosf(0.5f * ang[21], &s, &c); quad_gate<2>(a, s, c);
    sincosf(0.5f * ang[22], &s, &c); quad_gate<1>(a, s, c);
    sincosf(0.5f * ang[23], &s, &c); quad_gate<0>(a, s, c);

    if (SQUARE) {
#pragma unroll
        for (int r = 0; r < 64; ++r) a[r] *= a[r];
    }

    // ---- T3: -> regs = e6..11, lanes = e0..5, w = e12..14 (store layout)
    __syncthreads();
#pragma unroll
    for (int r = 0; r < 64; ++r) {
        int e = (w << 12) | (lane << 6) | r;
        lds[SWZ(e)] = a[r];
    }
    __syncthreads();
#pragma unroll
    for (int r = 0; r < 64; ++r) {
        int e = (w << 12) | (r << 6) | lane;
        a[r] = lds[SWZ(e)];
    }

    // store: 256B contiguous per wave-instr, standard layout
#pragma unroll
    for (int r = 0; r < 64; ++r)
        base[(w << 12) | (r << 6) | lane] = a[r];
}

extern "C" void kernel_launch(void* const* d_in, const int* in_sizes, int n_in,
                              void* d_out, int out_size, void* d_ws, size_t ws_size,
                              hipStream_t stream) {
    const float* angles = (const float*)d_in[0];
    float* state = (float*)d_out;   // state lives in d_out; last pass squares in place

    for (int b = 0; b < N_BLOCKS; ++b) {
        if (b == 0)
            pass1_kernel<true><<<2048, 256, 0, stream>>>(state, angles, b);
        else
            pass1_kernel<false><<<2048, 256, 0, stream>>>(state, angles, b);

        if (b == N_BLOCKS - 1)
            pass23_kernel<true><<<NSTATE >> 15, 512, 0, stream>>>(state, angles, b);
        else
            pass23_kernel<false><<<NSTATE >> 15, 512, 0, stream>>>(state, angles, b);
    }
}